// Round 1
// baseline (220.819 us; speedup 1.0000x reference)
//
#include <hip/hip_runtime.h>
#include <math.h>

#define D  256
#define T  768
#define N  384
#define FD 512

// ---------------- kernel 1: vpe + conv1d(k=3,pad=1) + ReLU + f1 = ve@W1.T+b1 ----
__global__ __launch_bounds__(256) void k_conv_f1(
    const float* __restrict__ vf, const float* __restrict__ vpos,
    const float* __restrict__ cw, const float* __restrict__ cb,
    const float* __restrict__ W1, const float* __restrict__ b1,
    float* __restrict__ ve, float* __restrict__ f1)
{
    __shared__ float vpe[10][D];   // rows t0-1 .. t0+8 (zero padded at edges)
    __shared__ float ver[8][D];    // relu'd conv output rows
    const int tid = threadIdx.x;
    const int t0 = blockIdx.x * 8;

    for (int r = 0; r < 10; ++r) {
        int t = t0 - 1 + r;
        float v = 0.0f;
        if (t >= 0 && t < T) v = vf[t*D + tid] + vpos[t*D + tid];
        vpe[r][tid] = v;
    }
    __syncthreads();

    // conv: thread = out channel o = tid, 8 time rows per block
    float acc[8];
#pragma unroll
    for (int i = 0; i < 8; ++i) acc[i] = 0.0f;

    const float* wrow = cw + tid * (D*3);   // conv_w[o][i][k] row, 768 floats
    for (int i0 = 0; i0 < D; i0 += 4) {
        float4 w0 = *(const float4*)(wrow + 3*i0);
        float4 w1_ = *(const float4*)(wrow + 3*i0 + 4);
        float4 w2_ = *(const float4*)(wrow + 3*i0 + 8);
        float w[12] = {w0.x,w0.y,w0.z,w0.w, w1_.x,w1_.y,w1_.z,w1_.w, w2_.x,w2_.y,w2_.z,w2_.w};
        float4 col[10];
#pragma unroll
        for (int r = 0; r < 10; ++r) col[r] = *(const float4*)&vpe[r][i0];
        const float* colf = (const float*)col;
#pragma unroll
        for (int di = 0; di < 4; ++di) {
#pragma unroll
            for (int k = 0; k < 3; ++k) {
                float wgt = w[di*3 + k];
#pragma unroll
                for (int tt = 0; tt < 8; ++tt)
                    acc[tt] += wgt * colf[(tt + k)*4 + di];
            }
        }
    }

    float bias = cb[tid];
#pragma unroll
    for (int tt = 0; tt < 8; ++tt) {
        float v = fmaxf(acc[tt] + bias, 0.0f);
        ve[(t0 + tt)*D + tid] = v;
        ver[tt][tid] = v;
    }
    __syncthreads();

    // f1 = ver @ W1.T + b1 ; thread handles f=tid and f=tid+256
    float a0[8], a1[8];
#pragma unroll
    for (int i = 0; i < 8; ++i) { a0[i] = 0.0f; a1[i] = 0.0f; }
    const float* w1r0 = W1 + tid * D;
    const float* w1r1 = W1 + (tid + 256) * D;
    for (int d0 = 0; d0 < D; d0 += 4) {
        float4 wa = *(const float4*)(w1r0 + d0);
        float4 wb = *(const float4*)(w1r1 + d0);
#pragma unroll
        for (int tt = 0; tt < 8; ++tt) {
            float4 vv = *(const float4*)&ver[tt][d0];
            a0[tt] += wa.x*vv.x + wa.y*vv.y + wa.z*vv.z + wa.w*vv.w;
            a1[tt] += wb.x*vv.x + wb.y*vv.y + wb.z*vv.z + wb.w*vv.w;
        }
    }
    float bb0 = b1[tid], bb1 = b1[tid + 256];
#pragma unroll
    for (int tt = 0; tt < 8; ++tt) {
        f1[(t0 + tt)*FD + tid]       = a0[tt] + bb0;
        f1[(t0 + tt)*FD + tid + 256] = a1[tt] + bb1;
    }
}

// ---------------- kernel 2: tn = row-l2-normalize(tf + tpos) -------------------
__global__ __launch_bounds__(256) void k_text(
    const float* __restrict__ tf, const float* __restrict__ tpos,
    float* __restrict__ tn)
{
    const int n = blockIdx.x, tid = threadIdx.x;
    float v = tf[n*D + tid] + tpos[n*D + tid];
    float p = v * v;
#pragma unroll
    for (int off = 32; off; off >>= 1) p += __shfl_down(p, off);
    __shared__ float ps[4];
    if ((tid & 63) == 0) ps[tid >> 6] = p;
    __syncthreads();
    float tot = ps[0] + ps[1] + ps[2] + ps[3];
    float nrm = fmaxf(sqrtf(tot), 1e-12f);
    tn[n*D + tid] = v / nrm;
}

// ---------------- kernel 3: q = (mean_rows tn) @ bil_w ; ut/uv = Wi.T @ wt/wv --
__global__ __launch_bounds__(256) void k_prep(
    const float* __restrict__ tn_, const float* __restrict__ bil_w,
    const float* __restrict__ Wi, const float* __restrict__ wt,
    const float* __restrict__ wv,
    float* __restrict__ q, float* __restrict__ ut, float* __restrict__ uv)
{
    const int tid = threadIdx.x;
    if (blockIdx.x == 0) {
        __shared__ float tb[D];
        float s = 0.0f;
        for (int n = 0; n < N; ++n) s += tn_[n*D + tid];
        tb[tid] = s * (1.0f / (float)N);
        __syncthreads();
        float qv = 0.0f;
        for (int e = 0; e < D; ++e) qv += tb[e] * bil_w[e*D + tid];
        q[tid] = qv;
    } else {
        const float* w = (blockIdx.x == 1) ? wt : wv;
        float* u = (blockIdx.x == 1) ? ut : uv;
        __shared__ float ws_[D];
        ws_[tid] = w[tid];
        __syncthreads();
        float s0 = 0.0f, s1 = 0.0f;
        for (int d = 0; d < D; ++d) {
            float x = ws_[d];
            s0 += x * Wi[d*FD + tid];
            s1 += x * Wi[d*FD + tid + 256];
        }
        u[tid] = s0;
        u[tid + 256] = s1;
    }
}

// ---------------- kernel 4: weights=sigmoid(tn@q), tg, f2 = tg@W2.T ------------
__global__ __launch_bounds__(256) void k_gnn_f2(
    const float* __restrict__ tn_, const float* __restrict__ q,
    const float* __restrict__ lin_w, const float* __restrict__ lin_b,
    const float* __restrict__ W2,
    float* __restrict__ tg, float* __restrict__ f2)
{
    __shared__ float tns[8][D];
    __shared__ float tgs[8][D];
    __shared__ float qs[D];
    __shared__ float wgt[8];
    const int tid = threadIdx.x;
    const int n0 = blockIdx.x * 8;
    qs[tid] = q[tid];
    for (int r = 0; r < 8; ++r) tns[r][tid] = tn_[(n0 + r)*D + tid];
    __syncthreads();

    const int wid = tid >> 6, lane = tid & 63;
    for (int r = wid*2; r < wid*2 + 2; ++r) {
        float p = 0.0f;
        for (int j = lane; j < D; j += 64) p += tns[r][j] * qs[j];
#pragma unroll
        for (int off = 32; off; off >>= 1) p += __shfl_down(p, off);
        if (lane == 0) wgt[r] = 1.0f / (1.0f + expf(-p));
    }
    __syncthreads();

    float accl[8];
#pragma unroll
    for (int i = 0; i < 8; ++i) accl[i] = 0.0f;
    const float* lwr = lin_w + tid * D;
    for (int d0 = 0; d0 < D; d0 += 4) {
        float4 w4 = *(const float4*)(lwr + d0);
#pragma unroll
        for (int r = 0; r < 8; ++r) {
            float4 tv = *(const float4*)&tns[r][d0];
            accl[r] += w4.x*tv.x + w4.y*tv.y + w4.z*tv.z + w4.w*tv.w;
        }
    }
    float lb = lin_b[tid];
#pragma unroll
    for (int r = 0; r < 8; ++r) {
        float g = wgt[r] * (accl[r] + lb);
        tgs[r][tid] = g;
        tg[(n0 + r)*D + tid] = g;
    }
    __syncthreads();

    float c0[8], c1[8];
#pragma unroll
    for (int i = 0; i < 8; ++i) { c0[i] = 0.0f; c1[i] = 0.0f; }
    const float* w2r0 = W2 + tid * D;
    const float* w2r1 = W2 + (tid + 256) * D;
    for (int d0 = 0; d0 < D; d0 += 4) {
        float4 wa = *(const float4*)(w2r0 + d0);
        float4 wb = *(const float4*)(w2r1 + d0);
#pragma unroll
        for (int r = 0; r < 8; ++r) {
            float4 tv = *(const float4*)&tgs[r][d0];
            c0[r] += wa.x*tv.x + wa.y*tv.y + wa.z*tv.z + wa.w*tv.w;
            c1[r] += wb.x*tv.x + wb.y*tv.y + wb.z*tv.z + wb.w*tv.w;
        }
    }
#pragma unroll
    for (int r = 0; r < 8; ++r) {
        f2[(n0 + r)*FD + tid]       = c0[r];
        f2[(n0 + r)*FD + tid + 256] = c1[r];
    }
}

// ---------------- kernel 5: scores st/sv = relu(f1[t]+f2[n]) . ut/uv -----------
__global__ __launch_bounds__(256) void k_score(
    const float* __restrict__ f1, const float* __restrict__ f2,
    const float* __restrict__ ut, const float* __restrict__ uv,
    float* __restrict__ st, float* __restrict__ sv)
{
    __shared__ float f1s[32][132];   // pad 132 -> rows spread over banks
    __shared__ float f2s[32][132];
    __shared__ float uts[FD];
    __shared__ float uvs[FD];
    const int tid = threadIdx.x;
    const int t0 = blockIdx.x * 32, n0 = blockIdx.y * 32;

    uts[tid] = ut[tid]; uts[tid+256] = ut[tid+256];
    uvs[tid] = uv[tid]; uvs[tid+256] = uv[tid+256];

    const int tA = 2 * (tid >> 4);   // f1 rows tA, tA+1
    const int nA = tid & 15;         // f2 rows nA, nA+16

    float at00=0.f, at01=0.f, at10=0.f, at11=0.f;
    float av00=0.f, av01=0.f, av10=0.f, av11=0.f;

    for (int c = 0; c < 4; ++c) {    // FD chunks of 128
        __syncthreads();
        for (int j = tid; j < 1024; j += 256) {
            int r = j >> 5, c4 = (j & 31) * 4;
            *(float4*)&f1s[r][c4] = *(const float4*)&f1[(t0 + r)*FD + c*128 + c4];
            *(float4*)&f2s[r][c4] = *(const float4*)&f2[(n0 + r)*FD + c*128 + c4];
        }
        __syncthreads();
#pragma unroll 8
        for (int fq = 0; fq < 32; ++fq) {
            float4 u_t = *(const float4*)&uts[c*128 + fq*4];
            float4 u_v = *(const float4*)&uvs[c*128 + fq*4];
            float4 a0 = *(const float4*)&f1s[tA][fq*4];
            float4 a1 = *(const float4*)&f1s[tA+1][fq*4];
            float4 b0 = *(const float4*)&f2s[nA][fq*4];
            float4 b1 = *(const float4*)&f2s[nA+16][fq*4];
#pragma unroll
            for (int e = 0; e < 4; ++e) {
                float ue_t = ((const float*)&u_t)[e];
                float ue_v = ((const float*)&u_v)[e];
                float a0e = ((const float*)&a0)[e], a1e = ((const float*)&a1)[e];
                float b0e = ((const float*)&b0)[e], b1e = ((const float*)&b1)[e];
                float h00 = fmaxf(a0e + b0e, 0.f);
                float h01 = fmaxf(a0e + b1e, 0.f);
                float h10 = fmaxf(a1e + b0e, 0.f);
                float h11 = fmaxf(a1e + b1e, 0.f);
                at00 += h00*ue_t; av00 += h00*ue_v;
                at01 += h01*ue_t; av01 += h01*ue_v;
                at10 += h10*ue_t; av10 += h10*ue_v;
                at11 += h11*ue_t; av11 += h11*ue_v;
            }
        }
    }
    const int t = t0 + tA, n = n0 + nA;
    st[t*N + n]          = at00;  st[t*N + n + 16]       = at01;
    st[(t+1)*N + n]      = at10;  st[(t+1)*N + n + 16]   = at11;
    sv[t*N + n]          = av00;  sv[t*N + n + 16]       = av01;
    sv[(t+1)*N + n]      = av10;  sv[(t+1)*N + n + 16]   = av11;
}

// ---------------- kernel 6: softmax over n + text_context + v_out --------------
__global__ __launch_bounds__(256) void k_att_t(
    const float* __restrict__ st, const float* __restrict__ tg,
    const float* __restrict__ ve, const float* __restrict__ vf,
    float* __restrict__ out_v)
{
    __shared__ float att[8][388];
    const int tid = threadIdx.x;
    const int t0 = blockIdx.x * 8;
    const int wid = tid >> 6, lane = tid & 63;

    for (int r = wid; r < 8; r += 4) {
        const float* row = st + (t0 + r)*N;
        float vals[6];
        float m = -1e30f;
#pragma unroll
        for (int j = 0; j < 6; ++j) { vals[j] = row[lane + 64*j]; m = fmaxf(m, vals[j]); }
#pragma unroll
        for (int off = 1; off < 64; off <<= 1) m = fmaxf(m, __shfl_xor(m, off));
        float s = 0.f;
#pragma unroll
        for (int j = 0; j < 6; ++j) { float e = expf(vals[j] - m); vals[j] = e; s += e; }
#pragma unroll
        for (int off = 1; off < 64; off <<= 1) s += __shfl_xor(s, off);
        float inv = 1.0f / s;
#pragma unroll
        for (int j = 0; j < 6; ++j) att[r][lane + 64*j] = vals[j] * inv;
    }
    __syncthreads();

    float acc[8];
#pragma unroll
    for (int i = 0; i < 8; ++i) acc[i] = 0.f;
    for (int nq = 0; nq < N; nq += 4) {
        float tv0 = tg[(nq+0)*D + tid];
        float tv1 = tg[(nq+1)*D + tid];
        float tv2 = tg[(nq+2)*D + tid];
        float tv3 = tg[(nq+3)*D + tid];
#pragma unroll
        for (int r = 0; r < 8; ++r) {
            float4 a4 = *(const float4*)&att[r][nq];
            acc[r] += a4.x*tv0 + a4.y*tv1 + a4.z*tv2 + a4.w*tv3;
        }
    }
#pragma unroll
    for (int r = 0; r < 8; ++r) {
        int t = t0 + r;
        out_v[t*D + tid] = 0.5f*acc[r] + 0.5f*ve[t*D + tid] + vf[t*D + tid];
    }
}

// ---------------- kernel 7: softmax over t + video_context + t_out -------------
__global__ __launch_bounds__(256) void k_att_v(
    const float* __restrict__ sv, const float* __restrict__ ve,
    const float* __restrict__ tg, const float* __restrict__ tf,
    float* __restrict__ out_t)
{
    __shared__ float att_s[128][8];
    __shared__ float pm[4][8], psum[4][8];
    __shared__ float fm[8], fs[8];
    const int tid = threadIdx.x;
    const int n0 = blockIdx.x * 8;
    const int wid = tid >> 6, lane = tid & 63;
    const int nn = tid & 7, tt = tid >> 3;   // tt 0..31

    // pass 1: per-column max / exp-sum (768 rows, 32 t-groups x 8 cols)
    float vals[24];
    float m = -1e30f;
#pragma unroll
    for (int k = 0; k < 24; ++k) {
        vals[k] = sv[(tt + 32*k)*N + n0 + nn];
        m = fmaxf(m, vals[k]);
    }
#pragma unroll
    for (int off = 8; off < 64; off <<= 1) m = fmaxf(m, __shfl_xor(m, off));
    float s = 0.f;
#pragma unroll
    for (int k = 0; k < 24; ++k) s += expf(vals[k] - m);
#pragma unroll
    for (int off = 8; off < 64; off <<= 1) s += __shfl_xor(s, off);
    if (lane < 8) { pm[wid][lane] = m; psum[wid][lane] = s; }
    __syncthreads();
    if (tid < 8) {
        float M = pm[0][tid];
        M = fmaxf(M, pm[1][tid]); M = fmaxf(M, pm[2][tid]); M = fmaxf(M, pm[3][tid]);
        float S = psum[0][tid]*expf(pm[0][tid]-M) + psum[1][tid]*expf(pm[1][tid]-M)
                + psum[2][tid]*expf(pm[2][tid]-M) + psum[3][tid]*expf(pm[3][tid]-M);
        fm[tid] = M; fs[tid] = 1.0f / S;
    }

    // pass 2: t_out[n][o] = 0.5 * sum_t att[t][n]*ve[t][o] + 0.5*tg + tf
    float acc[8];
#pragma unroll
    for (int i = 0; i < 8; ++i) acc[i] = 0.f;

    for (int tc = 0; tc < T; tc += 128) {
        __syncthreads();
        int e0 = tid * 4;
        int tl = e0 >> 3, n4 = e0 & 7;   // n4 in {0,4}
        float4 x = *(const float4*)&sv[(tc + tl)*N + n0 + n4];
        float4 a;
        a.x = expf(x.x - fm[n4+0]) * fs[n4+0];
        a.y = expf(x.y - fm[n4+1]) * fs[n4+1];
        a.z = expf(x.z - fm[n4+2]) * fs[n4+2];
        a.w = expf(x.w - fm[n4+3]) * fs[n4+3];
        *(float4*)&att_s[tl][n4] = a;
        __syncthreads();
#pragma unroll 4
        for (int j = 0; j < 128; ++j) {
            float vvv = ve[(tc + j)*D + tid];
            float4 q0 = *(const float4*)&att_s[j][0];
            float4 q1 = *(const float4*)&att_s[j][4];
            acc[0] += q0.x*vvv; acc[1] += q0.y*vvv; acc[2] += q0.z*vvv; acc[3] += q0.w*vvv;
            acc[4] += q1.x*vvv; acc[5] += q1.y*vvv; acc[6] += q1.z*vvv; acc[7] += q1.w*vvv;
        }
    }
#pragma unroll
    for (int r = 0; r < 8; ++r) {
        int n = n0 + r;
        out_t[n*D + tid] = 0.5f*acc[r] + 0.5f*tg[n*D + tid] + tf[n*D + tid];
    }
}

extern "C" void kernel_launch(void* const* d_in, const int* in_sizes, int n_in,
                              void* d_out, int out_size, void* d_ws, size_t ws_size,
                              hipStream_t stream)
{
    (void)in_sizes; (void)n_in; (void)out_size; (void)ws_size;
    const float* vf   = (const float*)d_in[0];
    const float* tf   = (const float*)d_in[1];
    const float* vpos = (const float*)d_in[2];
    const float* tpos = (const float*)d_in[3];
    const float* cw   = (const float*)d_in[4];
    const float* cb   = (const float*)d_in[5];
    const float* bil  = (const float*)d_in[6];
    const float* lw   = (const float*)d_in[7];
    const float* lb   = (const float*)d_in[8];
    const float* W1   = (const float*)d_in[9];
    const float* b1   = (const float*)d_in[10];
    const float* W2   = (const float*)d_in[11];
    const float* Wi   = (const float*)d_in[12];
    // d_in[13]=bi, d_in[15]=bt, d_in[17]=bv are softmax-invariant constant shifts -> unused
    const float* wt   = (const float*)d_in[14];
    const float* wv   = (const float*)d_in[16];

    float* ws = (float*)d_ws;
    float* ve = ws;                 // T*D
    float* tn = ve + T*D;           // N*D
    float* tg = tn + N*D;           // N*D
    float* f1 = tg + N*D;           // T*FD
    float* f2 = f1 + T*FD;          // N*FD
    float* q  = f2 + N*FD;          // D
    float* ut = q + D;              // FD
    float* uv = ut + FD;            // FD
    float* st = uv + FD;            // T*N
    float* sv = st + T*N;           // T*N   (total ~6.3 MB)

    float* out_v = (float*)d_out;
    float* out_t = out_v + T*D;

    hipLaunchKernelGGL(k_conv_f1, dim3(96),  dim3(256), 0, stream, vf, vpos, cw, cb, W1, b1, ve, f1);
    hipLaunchKernelGGL(k_text,    dim3(384), dim3(256), 0, stream, tf, tpos, tn);
    hipLaunchKernelGGL(k_prep,    dim3(3),   dim3(256), 0, stream, tn, bil, Wi, wt, wv, q, ut, uv);
    hipLaunchKernelGGL(k_gnn_f2,  dim3(48),  dim3(256), 0, stream, tn, q, lw, lb, W2, tg, f2);
    hipLaunchKernelGGL(k_score,   dim3(24,12), dim3(256), 0, stream, f1, f2, ut, uv, st, sv);
    hipLaunchKernelGGL(k_att_t,   dim3(96),  dim3(256), 0, stream, st, tg, ve, vf, out_v);
    hipLaunchKernelGGL(k_att_v,   dim3(48),  dim3(256), 0, stream, sv, ve, tg, tf, out_t);
}

// Round 2
// 163.269 us; speedup vs baseline: 1.3525x; 1.3525x over previous
//
#include <hip/hip_runtime.h>
#include <math.h>

#define D  256
#define T  768
#define N  384
#define FD 512

// ---------------- kernel 1: text normalize (blocks 0..383) + ut/uv (blocks 384..387)
__global__ __launch_bounds__(256) void k_text_uv(
    const float* __restrict__ tf, const float* __restrict__ tpos,
    const float* __restrict__ Wi, const float* __restrict__ wt,
    const float* __restrict__ wv,
    float* __restrict__ tn, float* __restrict__ ut, float* __restrict__ uv)
{
    const int b = blockIdx.x, tid = threadIdx.x;
    __shared__ float ps[4];
    __shared__ float ws_[D];
    if (b < N) {
        float v = tf[b*D + tid] + tpos[b*D + tid];
        float p = v * v;
#pragma unroll
        for (int off = 32; off; off >>= 1) p += __shfl_down(p, off);
        if ((tid & 63) == 0) ps[tid >> 6] = p;
        __syncthreads();
        float tot = ps[0] + ps[1] + ps[2] + ps[3];
        tn[b*D + tid] = v / fmaxf(sqrtf(tot), 1e-12f);
    } else {
        const int which = b - N;                 // 0,1 -> ut ; 2,3 -> uv
        const float* w = (which < 2) ? wt : wv;
        float* u = (which < 2) ? ut : uv;
        const int f = ((which & 1) << 8) + tid;  // 0..255 or 256..511
        ws_[tid] = w[tid];
        __syncthreads();
        float s = 0.f;
#pragma unroll 8
        for (int d = 0; d < D; ++d) s += ws_[d] * Wi[d*FD + f];
        u[f] = s;
    }
}

// ---------------- kernel 2: vpe + conv1d(k=3,pad=1) + ReLU -> ve -----------------
__global__ __launch_bounds__(256) void k_conv(
    const float* __restrict__ vf, const float* __restrict__ vpos,
    const float* __restrict__ cw, const float* __restrict__ cb,
    float* __restrict__ ve)
{
    __shared__ float vpe[10][D];
    const int tid = threadIdx.x;
    const int t0 = blockIdx.x * 8;
    const int o = (tid & 127) + (blockIdx.y << 7);
    const int rbase = (tid >> 7) * 4;            // rows rbase..rbase+3 of the 8-row tile

    for (int r = 0; r < 10; ++r) {
        int t = t0 - 1 + r;
        float v = 0.f;
        if (t >= 0 && t < T) v = vf[t*D + tid] + vpos[t*D + tid];
        vpe[r][tid] = v;
    }
    __syncthreads();

    float acc[4] = {0.f, 0.f, 0.f, 0.f};
    const float* wrow = cw + o * (D*3);
    for (int i0 = 0; i0 < D; i0 += 4) {
        float4 w0 = *(const float4*)(wrow + 3*i0);
        float4 w1 = *(const float4*)(wrow + 3*i0 + 4);
        float4 w2 = *(const float4*)(wrow + 3*i0 + 8);
        float w[12] = {w0.x,w0.y,w0.z,w0.w, w1.x,w1.y,w1.z,w1.w, w2.x,w2.y,w2.z,w2.w};
        float4 col[6];
#pragma unroll
        for (int r6 = 0; r6 < 6; ++r6) col[r6] = *(const float4*)&vpe[rbase + r6][i0];
        const float* colf = (const float*)col;
#pragma unroll
        for (int di = 0; di < 4; ++di)
#pragma unroll
            for (int k = 0; k < 3; ++k) {
                float wgt = w[di*3 + k];
#pragma unroll
                for (int tt = 0; tt < 4; ++tt)
                    acc[tt] += wgt * colf[(tt + k)*4 + di];
            }
    }
    float bias = cb[o];
#pragma unroll
    for (int tt = 0; tt < 4; ++tt)
        ve[(t0 + rbase + tt)*D + o] = fmaxf(acc[tt] + bias, 0.f);
}

// ---------------- kernel 3: f1 = ve @ W1.T + b1 ----------------------------------
__global__ __launch_bounds__(256) void k_f1(
    const float* __restrict__ ve, const float* __restrict__ W1,
    const float* __restrict__ b1, float* __restrict__ f1)
{
    __shared__ float ver[8][D];
    const int tid = threadIdx.x;
    const int t0 = blockIdx.x * 8;
    for (int r = 0; r < 8; ++r) ver[r][tid] = ve[(t0 + r)*D + tid];
    __syncthreads();

    float a0[8], a1[8];
#pragma unroll
    for (int i = 0; i < 8; ++i) { a0[i] = 0.f; a1[i] = 0.f; }
    const float* w1r0 = W1 + tid * D;
    const float* w1r1 = W1 + (tid + 256) * D;
    for (int d0 = 0; d0 < D; d0 += 4) {
        float4 wa = *(const float4*)(w1r0 + d0);
        float4 wb = *(const float4*)(w1r1 + d0);
#pragma unroll
        for (int tt = 0; tt < 8; ++tt) {
            float4 vv = *(const float4*)&ver[tt][d0];
            a0[tt] += wa.x*vv.x + wa.y*vv.y + wa.z*vv.z + wa.w*vv.w;
            a1[tt] += wb.x*vv.x + wb.y*vv.y + wb.z*vv.z + wb.w*vv.w;
        }
    }
    float bb0 = b1[tid], bb1 = b1[tid + 256];
#pragma unroll
    for (int tt = 0; tt < 8; ++tt) {
        f1[(t0 + tt)*FD + tid]       = a0[tt] + bb0;
        f1[(t0 + tt)*FD + tid + 256] = a1[tt] + bb1;
    }
}

// ---------------- kernel 4: q = (mean_rows tn) @ bil_w  (1 block, 1024 thr) ------
__global__ __launch_bounds__(1024) void k_q(
    const float* __restrict__ tn_, const float* __restrict__ bil_w,
    float* __restrict__ q)
{
    __shared__ float part[4][D];
    __shared__ float tb[D];
    const int tid = threadIdx.x;
    const int c = tid & 255, g = tid >> 8;       // g 0..3
    float s = 0.f;
#pragma unroll 8
    for (int n = g; n < N; n += 4) s += tn_[n*D + c];
    part[g][c] = s;
    __syncthreads();
    if (tid < D) tb[tid] = (part[0][tid] + part[1][tid] + part[2][tid] + part[3][tid]) * (1.0f / (float)N);
    __syncthreads();
    float s2 = 0.f;
#pragma unroll 8
    for (int e = g*64; e < g*64 + 64; ++e) s2 += tb[e] * bil_w[e*D + c];
    part[g][c] = s2;
    __syncthreads();
    if (tid < D) q[tid] = part[0][tid] + part[1][tid] + part[2][tid] + part[3][tid];
}

// ---------------- kernel 5: weights=sigmoid(tn@q), tg, f2 = tg@W2.T --------------
__global__ __launch_bounds__(256) void k_gnn_f2(
    const float* __restrict__ tn_, const float* __restrict__ q,
    const float* __restrict__ lin_w, const float* __restrict__ lin_b,
    const float* __restrict__ W2,
    float* __restrict__ tg, float* __restrict__ f2)
{
    __shared__ float tns[4][D];
    __shared__ float tgs[4][D];
    __shared__ float qs[D];
    __shared__ float wgt[4];
    const int tid = threadIdx.x;
    const int n0 = blockIdx.x * 4;
    qs[tid] = q[tid];
    for (int r = 0; r < 4; ++r) tns[r][tid] = tn_[(n0 + r)*D + tid];
    __syncthreads();

    const int wid = tid >> 6, lane = tid & 63;
    {
        float p = 0.f;
        for (int j = lane; j < D; j += 64) p += tns[wid][j] * qs[j];
#pragma unroll
        for (int off = 32; off; off >>= 1) p += __shfl_down(p, off);
        if (lane == 0) wgt[wid] = 1.0f / (1.0f + expf(-p));
    }
    __syncthreads();

    float accl[4] = {0.f,0.f,0.f,0.f};
    const float* lwr = lin_w + tid * D;
    for (int d0 = 0; d0 < D; d0 += 4) {
        float4 w4 = *(const float4*)(lwr + d0);
#pragma unroll
        for (int r = 0; r < 4; ++r) {
            float4 tv = *(const float4*)&tns[r][d0];
            accl[r] += w4.x*tv.x + w4.y*tv.y + w4.z*tv.z + w4.w*tv.w;
        }
    }
    float lb = lin_b[tid];
#pragma unroll
    for (int r = 0; r < 4; ++r) {
        float g = wgt[r] * (accl[r] + lb);
        tgs[r][tid] = g;
        tg[(n0 + r)*D + tid] = g;
    }
    __syncthreads();

    float c0[4] = {0.f,0.f,0.f,0.f}, c1[4] = {0.f,0.f,0.f,0.f};
    const float* w2r0 = W2 + tid * D;
    const float* w2r1 = W2 + (tid + 256) * D;
    for (int d0 = 0; d0 < D; d0 += 4) {
        float4 wa = *(const float4*)(w2r0 + d0);
        float4 wb = *(const float4*)(w2r1 + d0);
#pragma unroll
        for (int r = 0; r < 4; ++r) {
            float4 tv = *(const float4*)&tgs[r][d0];
            c0[r] += wa.x*tv.x + wa.y*tv.y + wa.z*tv.z + wa.w*tv.w;
            c1[r] += wb.x*tv.x + wb.y*tv.y + wb.z*tv.z + wb.w*tv.w;
        }
    }
#pragma unroll
    for (int r = 0; r < 4; ++r) {
        f2[(n0 + r)*FD + tid]       = c0[r];
        f2[(n0 + r)*FD + tid + 256] = c1[r];
    }
}

// ---------------- kernel 6: scores; st row-major, sv stored TRANSPOSED -----------
__global__ __launch_bounds__(256) void k_score(
    const float* __restrict__ f1, const float* __restrict__ f2,
    const float* __restrict__ ut, const float* __restrict__ uv,
    float* __restrict__ st, float* __restrict__ svT)
{
    __shared__ float f1s[32][132];
    __shared__ float f2s[32][132];
    __shared__ float uts[FD];
    __shared__ float uvs[FD];
    const int tid = threadIdx.x;
    const int t0 = blockIdx.x * 32, n0 = blockIdx.y * 32;

    uts[tid] = ut[tid]; uts[tid+256] = ut[tid+256];
    uvs[tid] = uv[tid]; uvs[tid+256] = uv[tid+256];

    const int tA = 2 * (tid >> 4);   // f1 rows tA, tA+1
    const int nA = tid & 15;         // f2 rows nA, nA+16

    float at00=0.f, at01=0.f, at10=0.f, at11=0.f;
    float av00=0.f, av01=0.f, av10=0.f, av11=0.f;

    for (int c = 0; c < 4; ++c) {    // FD chunks of 128
        __syncthreads();
        for (int j = tid; j < 1024; j += 256) {
            int r = j >> 5, c4 = (j & 31) * 4;
            *(float4*)&f1s[r][c4] = *(const float4*)&f1[(t0 + r)*FD + c*128 + c4];
            *(float4*)&f2s[r][c4] = *(const float4*)&f2[(n0 + r)*FD + c*128 + c4];
        }
        __syncthreads();
#pragma unroll 8
        for (int fq = 0; fq < 32; ++fq) {
            float4 u_t = *(const float4*)&uts[c*128 + fq*4];
            float4 u_v = *(const float4*)&uvs[c*128 + fq*4];
            float4 a0 = *(const float4*)&f1s[tA][fq*4];
            float4 a1 = *(const float4*)&f1s[tA+1][fq*4];
            float4 b0 = *(const float4*)&f2s[nA][fq*4];
            float4 b1 = *(const float4*)&f2s[nA+16][fq*4];
#pragma unroll
            for (int e = 0; e < 4; ++e) {
                float ue_t = ((const float*)&u_t)[e];
                float ue_v = ((const float*)&u_v)[e];
                float a0e = ((const float*)&a0)[e], a1e = ((const float*)&a1)[e];
                float b0e = ((const float*)&b0)[e], b1e = ((const float*)&b1)[e];
                float h00 = fmaxf(a0e + b0e, 0.f);
                float h01 = fmaxf(a0e + b1e, 0.f);
                float h10 = fmaxf(a1e + b0e, 0.f);
                float h11 = fmaxf(a1e + b1e, 0.f);
                at00 += h00*ue_t; av00 += h00*ue_v;
                at01 += h01*ue_t; av01 += h01*ue_v;
                at10 += h10*ue_t; av10 += h10*ue_v;
                at11 += h11*ue_t; av11 += h11*ue_v;
            }
        }
    }
    const int t = t0 + tA, n = n0 + nA;
    st[t*N + n]        = at00;  st[t*N + n + 16]     = at01;
    st[(t+1)*N + n]    = at10;  st[(t+1)*N + n + 16] = at11;
    // transposed: svT[n][t], pairs (t, t+1) contiguous
    *(float2*)&svT[n*T + t]        = make_float2(av00, av10);
    *(float2*)&svT[(n+16)*T + t]   = make_float2(av01, av11);
}

// ---------------- kernel 7: row softmax stats for st (768 rows) & svT (384 rows) -
__global__ __launch_bounds__(256) void k_stats(
    const float* __restrict__ st, const float* __restrict__ svT,
    float* __restrict__ fm_t, float* __restrict__ fi_t,
    float* __restrict__ fm_v, float* __restrict__ fi_v)
{
    const int tid = threadIdx.x, wid = tid >> 6, lane = tid & 63;
    const int b = blockIdx.x;
    if (b < 96) {                                  // st rows, length N=384
        const int r0 = b*8 + wid*2;
        for (int k = 0; k < 2; ++k) {
            const int r = r0 + k;
            const float* row = st + r*N;
            float v[6]; float m = -1e30f;
#pragma unroll
            for (int j = 0; j < 6; ++j) { v[j] = row[lane + 64*j]; m = fmaxf(m, v[j]); }
#pragma unroll
            for (int off = 1; off < 64; off <<= 1) m = fmaxf(m, __shfl_xor(m, off));
            float s = 0.f;
#pragma unroll
            for (int j = 0; j < 6; ++j) s += expf(v[j] - m);
#pragma unroll
            for (int off = 1; off < 64; off <<= 1) s += __shfl_xor(s, off);
            if (lane == 0) { fm_t[r] = m; fi_t[r] = 1.0f / s; }
        }
    } else {                                       // svT rows, length T=768
        const int r0 = (b - 96)*8 + wid*2;
        for (int k = 0; k < 2; ++k) {
            const int r = r0 + k;
            const float* row = svT + r*T;
            float v[12]; float m = -1e30f;
#pragma unroll
            for (int j = 0; j < 12; ++j) { v[j] = row[lane + 64*j]; m = fmaxf(m, v[j]); }
#pragma unroll
            for (int off = 1; off < 64; off <<= 1) m = fmaxf(m, __shfl_xor(m, off));
            float s = 0.f;
#pragma unroll
            for (int j = 0; j < 12; ++j) s += expf(v[j] - m);
#pragma unroll
            for (int off = 1; off < 64; off <<= 1) s += __shfl_xor(s, off);
            if (lane == 0) { fm_v[r] = m; fi_v[r] = 1.0f / s; }
        }
    }
}

// ---------------- kernel 8: fused attention-context + epilogues ------------------
// blocks 0..383   : out_v tiles (8 t-rows x 64 o-cols), softmax over n (st)
// blocks 384..575 : out_t tiles (8 n-rows x 64 o-cols), softmax over t (svT)
__global__ __launch_bounds__(256) void k_att(
    const float* __restrict__ st, const float* __restrict__ svT,
    const float* __restrict__ fm_t, const float* __restrict__ fi_t,
    const float* __restrict__ fm_v, const float* __restrict__ fi_v,
    const float* __restrict__ tg, const float* __restrict__ ve,
    const float* __restrict__ vf, const float* __restrict__ tf,
    float* __restrict__ out_v, float* __restrict__ out_t)
{
    __shared__ float attb[768][8];     // [col][row-of-tile]
    __shared__ float pt[4][8][64];
    const int tid = threadIdx.x;
    const int oo = tid & 63, g = tid >> 6;

    if (blockIdx.x < 384) {
        const int bx = blockIdx.x >> 2, by = blockIdx.x & 3;
        const int t0 = bx * 8, o0 = by * 64;
        const int o = o0 + oo;
#pragma unroll
        for (int r = 0; r < 8; ++r) {
            float m = fm_t[t0 + r], fi = fi_t[t0 + r];
            attb[tid][r] = expf(st[(t0 + r)*N + tid] - m) * fi;
            if (tid < 128) attb[tid + 256][r] = expf(st[(t0 + r)*N + tid + 256] - m) * fi;
        }
        __syncthreads();
        float acc[8] = {0.f,0.f,0.f,0.f,0.f,0.f,0.f,0.f};
#pragma unroll 4
        for (int n = g; n < N; n += 4) {
            float tv = tg[n*D + o];
            float4 a0 = *(const float4*)&attb[n][0];
            float4 a1 = *(const float4*)&attb[n][4];
            acc[0] += a0.x*tv; acc[1] += a0.y*tv; acc[2] += a0.z*tv; acc[3] += a0.w*tv;
            acc[4] += a1.x*tv; acc[5] += a1.y*tv; acc[6] += a1.z*tv; acc[7] += a1.w*tv;
        }
#pragma unroll
        for (int r = 0; r < 8; ++r) pt[g][r][oo] = acc[r];
        __syncthreads();
#pragma unroll
        for (int rr = g; rr < 8; rr += 4) {
            float s = pt[0][rr][oo] + pt[1][rr][oo] + pt[2][rr][oo] + pt[3][rr][oo];
            int t = t0 + rr;
            out_v[t*D + o] = 0.5f*s + 0.5f*ve[t*D + o] + vf[t*D + o];
        }
    } else {
        const int b2 = blockIdx.x - 384;
        const int bx = b2 >> 2, by = b2 & 3;
        const int n0 = bx * 8, o0 = by * 64;
        const int o = o0 + oo;
#pragma unroll
        for (int r = 0; r < 8; ++r) {
            float m = fm_v[n0 + r], fi = fi_v[n0 + r];
            const float* row = svT + (n0 + r)*T;
            attb[tid][r]       = expf(row[tid]       - m) * fi;
            attb[tid + 256][r] = expf(row[tid + 256] - m) * fi;
            attb[tid + 512][r] = expf(row[tid + 512] - m) * fi;
        }
        __syncthreads();
        float acc[8] = {0.f,0.f,0.f,0.f,0.f,0.f,0.f,0.f};
#pragma unroll 4
        for (int t = g; t < T; t += 4) {
            float vv = ve[t*D + o];
            float4 a0 = *(const float4*)&attb[t][0];
            float4 a1 = *(const float4*)&attb[t][4];
            acc[0] += a0.x*vv; acc[1] += a0.y*vv; acc[2] += a0.z*vv; acc[3] += a0.w*vv;
            acc[4] += a1.x*vv; acc[5] += a1.y*vv; acc[6] += a1.z*vv; acc[7] += a1.w*vv;
        }
#pragma unroll
        for (int r = 0; r < 8; ++r) pt[g][r][oo] = acc[r];
        __syncthreads();
#pragma unroll
        for (int rr = g; rr < 8; rr += 4) {
            float s = pt[0][rr][oo] + pt[1][rr][oo] + pt[2][rr][oo] + pt[3][rr][oo];
            int n = n0 + rr;
            out_t[n*D + o] = 0.5f*s + 0.5f*tg[n*D + o] + tf[n*D + o];
        }
    }
}

extern "C" void kernel_launch(void* const* d_in, const int* in_sizes, int n_in,
                              void* d_out, int out_size, void* d_ws, size_t ws_size,
                              hipStream_t stream)
{
    (void)in_sizes; (void)n_in; (void)out_size; (void)ws_size;
    const float* vf   = (const float*)d_in[0];
    const float* tf   = (const float*)d_in[1];
    const float* vpos = (const float*)d_in[2];
    const float* tpos = (const float*)d_in[3];
    const float* cw   = (const float*)d_in[4];
    const float* cb   = (const float*)d_in[5];
    const float* bil  = (const float*)d_in[6];
    const float* lw   = (const float*)d_in[7];
    const float* lb   = (const float*)d_in[8];
    const float* W1   = (const float*)d_in[9];
    const float* b1   = (const float*)d_in[10];
    const float* W2   = (const float*)d_in[11];
    const float* Wi   = (const float*)d_in[12];
    // d_in[13]=bi, d_in[15]=bt, d_in[17]=bv are softmax-invariant constant shifts -> unused
    const float* wt   = (const float*)d_in[14];
    const float* wv   = (const float*)d_in[16];

    float* ws   = (float*)d_ws;
    float* ve   = ws;               // T*D
    float* tn   = ve + T*D;         // N*D
    float* tg   = tn + N*D;         // N*D
    float* f1   = tg + N*D;         // T*FD
    float* f2   = f1 + T*FD;        // N*FD
    float* q    = f2 + N*FD;        // D
    float* ut   = q + D;            // FD
    float* uv   = ut + FD;          // FD
    float* st   = uv + FD;          // T*N
    float* svT  = st + T*N;         // N*T
    float* fm_t = svT + N*T;        // T
    float* fi_t = fm_t + T;         // T
    float* fm_v = fi_t + T;         // N
    float* fi_v = fm_v + N;         // N

    float* out_v = (float*)d_out;
    float* out_t = out_v + T*D;

    hipLaunchKernelGGL(k_text_uv, dim3(N + 4),    dim3(256),  0, stream, tf, tpos, Wi, wt, wv, tn, ut, uv);
    hipLaunchKernelGGL(k_conv,    dim3(96, 2),    dim3(256),  0, stream, vf, vpos, cw, cb, ve);
    hipLaunchKernelGGL(k_f1,      dim3(96),       dim3(256),  0, stream, ve, W1, b1, f1);
    hipLaunchKernelGGL(k_q,       dim3(1),        dim3(1024), 0, stream, tn, bil, q);
    hipLaunchKernelGGL(k_gnn_f2,  dim3(96),       dim3(256),  0, stream, tn, q, lw, lb, W2, tg, f2);
    hipLaunchKernelGGL(k_score,   dim3(24, 12),   dim3(256),  0, stream, f1, f2, ut, uv, st, svT);
    hipLaunchKernelGGL(k_stats,   dim3(144),      dim3(256),  0, stream, st, svT, fm_t, fi_t, fm_v, fi_v);
    hipLaunchKernelGGL(k_att,     dim3(576),      dim3(256),  0, stream, st, svT, fm_t, fi_t, fm_v, fi_v,
                       tg, ve, vf, tf, out_v, out_t);
}

// Round 3
// 162.483 us; speedup vs baseline: 1.3590x; 1.0048x over previous
//
#include <hip/hip_runtime.h>
#include <math.h>

#define D  256
#define T  768
#define N  384
#define FD 512

// ---------- node 1: k_front ----------------------------------------------------
// blocks [0,192)   : conv1d(k=3,pad=1)+ReLU -> ve, then f1 = ve@W1.T+b1 (4-row tiles)
// blocks [192,288) : text row-l2-normalize (4 rows/block)
// blocks 288,289   : ut = Wi.T@wt, uv = Wi.T@wv
__global__ __launch_bounds__(256) void k_front(
    const float* __restrict__ vf, const float* __restrict__ vpos,
    const float* __restrict__ cw, const float* __restrict__ cb,
    const float* __restrict__ W1, const float* __restrict__ b1,
    const float* __restrict__ tf, const float* __restrict__ tpos,
    const float* __restrict__ Wi, const float* __restrict__ wt,
    const float* __restrict__ wv,
    float* __restrict__ ve, float* __restrict__ f1,
    float* __restrict__ tn, float* __restrict__ ut, float* __restrict__ uv)
{
    const int b = blockIdx.x, tid = threadIdx.x;
    if (b < 192) {
        __shared__ float vpe[6][D];
        __shared__ float ver[4][D];
        const int t0 = b * 4;
#pragma unroll
        for (int r = 0; r < 6; ++r) {
            int t = t0 - 1 + r;
            float v = 0.f;
            if (t >= 0 && t < T) v = vf[t*D + tid] + vpos[t*D + tid];
            vpe[r][tid] = v;
        }
        __syncthreads();

        float acc[4] = {0.f, 0.f, 0.f, 0.f};
        const float* wrow = cw + tid * (D*3);
        for (int i0 = 0; i0 < D; i0 += 4) {
            float4 w0 = *(const float4*)(wrow + 3*i0);
            float4 w1 = *(const float4*)(wrow + 3*i0 + 4);
            float4 w2 = *(const float4*)(wrow + 3*i0 + 8);
            float w[12] = {w0.x,w0.y,w0.z,w0.w, w1.x,w1.y,w1.z,w1.w, w2.x,w2.y,w2.z,w2.w};
            float4 col[6];
#pragma unroll
            for (int r6 = 0; r6 < 6; ++r6) col[r6] = *(const float4*)&vpe[r6][i0];
            const float* colf = (const float*)col;
#pragma unroll
            for (int di = 0; di < 4; ++di)
#pragma unroll
                for (int k = 0; k < 3; ++k) {
                    float wgt = w[di*3 + k];
#pragma unroll
                    for (int rr = 0; rr < 4; ++rr)
                        acc[rr] += wgt * colf[(rr + k)*4 + di];
                }
        }
        float bias = cb[tid];
#pragma unroll
        for (int rr = 0; rr < 4; ++rr) {
            float v = fmaxf(acc[rr] + bias, 0.f);
            ve[(t0 + rr)*D + tid] = v;
            ver[rr][tid] = v;
        }
        __syncthreads();

        float a0[4] = {0.f,0.f,0.f,0.f}, a1[4] = {0.f,0.f,0.f,0.f};
        const float* w1r0 = W1 + tid * D;
        const float* w1r1 = W1 + (tid + 256) * D;
        for (int d0 = 0; d0 < D; d0 += 4) {
            float4 wa = *(const float4*)(w1r0 + d0);
            float4 wb = *(const float4*)(w1r1 + d0);
#pragma unroll
            for (int rr = 0; rr < 4; ++rr) {
                float4 vv = *(const float4*)&ver[rr][d0];
                a0[rr] += wa.x*vv.x + wa.y*vv.y + wa.z*vv.z + wa.w*vv.w;
                a1[rr] += wb.x*vv.x + wb.y*vv.y + wb.z*vv.z + wb.w*vv.w;
            }
        }
        float bb0 = b1[tid], bb1 = b1[tid + 256];
#pragma unroll
        for (int rr = 0; rr < 4; ++rr) {
            f1[(t0 + rr)*FD + tid]       = a0[rr] + bb0;
            f1[(t0 + rr)*FD + tid + 256] = a1[rr] + bb1;
        }
    } else if (b < 288) {
        const int wid = tid >> 6, lane = tid & 63;
        const int r = (b - 192)*4 + wid;
        float v[4]; float ss = 0.f;
#pragma unroll
        for (int k = 0; k < 4; ++k) {
            v[k] = tf[r*D + lane + 64*k] + tpos[r*D + lane + 64*k];
            ss += v[k]*v[k];
        }
#pragma unroll
        for (int off = 1; off < 64; off <<= 1) ss += __shfl_xor(ss, off);
        float inv = 1.0f / fmaxf(sqrtf(ss), 1e-12f);
#pragma unroll
        for (int k = 0; k < 4; ++k) tn[r*D + lane + 64*k] = v[k] * inv;
    } else {
        __shared__ float wsm[D];
        const float* w = (b == 288) ? wt : wv;
        float* u = (b == 288) ? ut : uv;
        wsm[tid] = w[tid];
        __syncthreads();
        float s0 = 0.f, s1 = 0.f;
#pragma unroll 4
        for (int d = 0; d < D; ++d) {
            float x = wsm[d];
            s0 += x * Wi[d*FD + tid];
            s1 += x * Wi[d*FD + tid + 256];
        }
        u[tid] = s0;
        u[tid + 256] = s1;
    }
}

// ---------- node 2: k_gnnq  (q recomputed per block, then gnn + f2) -------------
__global__ __launch_bounds__(256) void k_gnnq(
    const float* __restrict__ tn_, const float* __restrict__ bil_w,
    const float* __restrict__ lin_w, const float* __restrict__ lin_b,
    const float* __restrict__ W2,
    float* __restrict__ tg, float* __restrict__ f2)
{
    __shared__ float tb[D];
    __shared__ float qs[D];
    __shared__ float tns[4][D];
    __shared__ float tgs[4][D];
    __shared__ float wgt[4];
    const int tid = threadIdx.x;
    const int n0 = blockIdx.x * 4;

    // tbar (mean of tn rows), then q = tbar @ bil_w
    {
        float s = 0.f;
#pragma unroll 4
        for (int n = 0; n < N; ++n) s += tn_[n*D + tid];
        tb[tid] = s * (1.0f / (float)N);
    }
    for (int r = 0; r < 4; ++r) tns[r][tid] = tn_[(n0 + r)*D + tid];
    __syncthreads();
    {
        float qv = 0.f;
#pragma unroll 4
        for (int e = 0; e < D; ++e) qv += tb[e] * bil_w[e*D + tid];
        qs[tid] = qv;
    }
    __syncthreads();

    const int wid = tid >> 6, lane = tid & 63;
    {
        float p = 0.f;
#pragma unroll
        for (int k = 0; k < 4; ++k) p += tns[wid][lane + 64*k] * qs[lane + 64*k];
#pragma unroll
        for (int off = 32; off; off >>= 1) p += __shfl_down(p, off);
        if (lane == 0) wgt[wid] = 1.0f / (1.0f + expf(-p));
    }
    __syncthreads();

    float accl[4] = {0.f,0.f,0.f,0.f};
    const float* lwr = lin_w + tid * D;
    for (int d0 = 0; d0 < D; d0 += 4) {
        float4 w4 = *(const float4*)(lwr + d0);
#pragma unroll
        for (int r = 0; r < 4; ++r) {
            float4 tv = *(const float4*)&tns[r][d0];
            accl[r] += w4.x*tv.x + w4.y*tv.y + w4.z*tv.z + w4.w*tv.w;
        }
    }
    float lb = lin_b[tid];
#pragma unroll
    for (int r = 0; r < 4; ++r) {
        float g = wgt[r] * (accl[r] + lb);
        tgs[r][tid] = g;
        tg[(n0 + r)*D + tid] = g;
    }
    __syncthreads();

    float c0[4] = {0.f,0.f,0.f,0.f}, c1[4] = {0.f,0.f,0.f,0.f};
    const float* w2r0 = W2 + tid * D;
    const float* w2r1 = W2 + (tid + 256) * D;
    for (int d0 = 0; d0 < D; d0 += 4) {
        float4 wa = *(const float4*)(w2r0 + d0);
        float4 wb = *(const float4*)(w2r1 + d0);
#pragma unroll
        for (int r = 0; r < 4; ++r) {
            float4 tv = *(const float4*)&tgs[r][d0];
            c0[r] += wa.x*tv.x + wa.y*tv.y + wa.z*tv.z + wa.w*tv.w;
            c1[r] += wb.x*tv.x + wb.y*tv.y + wb.z*tv.z + wb.w*tv.w;
        }
    }
#pragma unroll
    for (int r = 0; r < 4; ++r) {
        f2[(n0 + r)*FD + tid]       = c0[r];
        f2[(n0 + r)*FD + tid + 256] = c1[r];
    }
}

// ---------- node 3: k_score  (FD split over blockIdx.z, partial outputs) --------
__global__ __launch_bounds__(256) void k_score(
    const float* __restrict__ f1, const float* __restrict__ f2,
    const float* __restrict__ ut, const float* __restrict__ uv,
    float* __restrict__ stp, float* __restrict__ svp)
{
    __shared__ float f1s[32][132];
    __shared__ float f2s[32][132];
    __shared__ float us_t[128];
    __shared__ float us_v[128];
    const int tid = threadIdx.x;
    const int t0 = blockIdx.x * 32, n0 = blockIdx.y * 32, c = blockIdx.z;

    if (tid < 128) { us_t[tid] = ut[c*128 + tid]; us_v[tid] = uv[c*128 + tid]; }
    for (int j = tid; j < 1024; j += 256) {
        int r = j >> 5, c4 = (j & 31) * 4;
        *(float4*)&f1s[r][c4] = *(const float4*)&f1[(t0 + r)*FD + c*128 + c4];
        *(float4*)&f2s[r][c4] = *(const float4*)&f2[(n0 + r)*FD + c*128 + c4];
    }
    __syncthreads();

    const int tA = 2 * (tid >> 4);
    const int nA = tid & 15;

    float at00=0.f, at01=0.f, at10=0.f, at11=0.f;
    float av00=0.f, av01=0.f, av10=0.f, av11=0.f;

#pragma unroll 8
    for (int fq = 0; fq < 32; ++fq) {
        float4 u_t = *(const float4*)&us_t[fq*4];
        float4 u_v = *(const float4*)&us_v[fq*4];
        float4 a0 = *(const float4*)&f1s[tA][fq*4];
        float4 a1 = *(const float4*)&f1s[tA+1][fq*4];
        float4 b0 = *(const float4*)&f2s[nA][fq*4];
        float4 b1 = *(const float4*)&f2s[nA+16][fq*4];
#pragma unroll
        for (int e = 0; e < 4; ++e) {
            float ue_t = ((const float*)&u_t)[e];
            float ue_v = ((const float*)&u_v)[e];
            float a0e = ((const float*)&a0)[e], a1e = ((const float*)&a1)[e];
            float b0e = ((const float*)&b0)[e], b1e = ((const float*)&b1)[e];
            float h00 = fmaxf(a0e + b0e, 0.f);
            float h01 = fmaxf(a0e + b1e, 0.f);
            float h10 = fmaxf(a1e + b0e, 0.f);
            float h11 = fmaxf(a1e + b1e, 0.f);
            at00 += h00*ue_t; av00 += h00*ue_v;
            at01 += h01*ue_t; av01 += h01*ue_v;
            at10 += h10*ue_t; av10 += h10*ue_v;
            at11 += h11*ue_t; av11 += h11*ue_v;
        }
    }
    const int t = t0 + tA, n = n0 + nA;
    float* stz = stp + c * (T*N);
    float* svz = svp + c * (N*T);
    stz[t*N + n]        = at00;  stz[t*N + n + 16]     = at01;
    stz[(t+1)*N + n]    = at10;  stz[(t+1)*N + n + 16] = at11;
    *(float2*)&svz[n*T + t]      = make_float2(av00, av10);
    *(float2*)&svz[(n+16)*T + t] = make_float2(av01, av11);
}

// ---------- node 4: combine partials + softmax -> normalized attention ----------
// blocks [0,192)   : At[t][n] rows (length N)
// blocks [192,288) : Av[n][t] rows (length T)
__global__ __launch_bounds__(256) void k_stats(
    const float* __restrict__ stp, const float* __restrict__ svp,
    float* __restrict__ At, float* __restrict__ Av)
{
    const int tid = threadIdx.x, wid = tid >> 6, lane = tid & 63;
    const int b = blockIdx.x;
    if (b < 192) {
        const int r = b*4 + wid;
        const float* p0 = stp + r*N;
        const float* p1 = p0 + T*N;
        const float* p2 = p1 + T*N;
        const float* p3 = p2 + T*N;
        float v[6]; float m = -1e30f;
#pragma unroll
        for (int j = 0; j < 6; ++j) {
            int cc = lane + 64*j;
            v[j] = p0[cc] + p1[cc] + p2[cc] + p3[cc];
            m = fmaxf(m, v[j]);
        }
#pragma unroll
        for (int off = 1; off < 64; off <<= 1) m = fmaxf(m, __shfl_xor(m, off));
        float s = 0.f;
#pragma unroll
        for (int j = 0; j < 6; ++j) { v[j] = expf(v[j] - m); s += v[j]; }
#pragma unroll
        for (int off = 1; off < 64; off <<= 1) s += __shfl_xor(s, off);
        float inv = 1.0f / s;
#pragma unroll
        for (int j = 0; j < 6; ++j) At[r*N + lane + 64*j] = v[j] * inv;
    } else {
        const int r = (b - 192)*4 + wid;
        const float* p0 = svp + r*T;
        const float* p1 = p0 + N*T;
        const float* p2 = p1 + N*T;
        const float* p3 = p2 + N*T;
        float v[12]; float m = -1e30f;
#pragma unroll
        for (int j = 0; j < 12; ++j) {
            int cc = lane + 64*j;
            v[j] = p0[cc] + p1[cc] + p2[cc] + p3[cc];
            m = fmaxf(m, v[j]);
        }
#pragma unroll
        for (int off = 1; off < 64; off <<= 1) m = fmaxf(m, __shfl_xor(m, off));
        float s = 0.f;
#pragma unroll
        for (int j = 0; j < 12; ++j) { v[j] = expf(v[j] - m); s += v[j]; }
#pragma unroll
        for (int off = 1; off < 64; off <<= 1) s += __shfl_xor(s, off);
        float inv = 1.0f / s;
#pragma unroll
        for (int j = 0; j < 12; ++j) Av[r*T + lane + 64*j] = v[j] * inv;
    }
}

// ---------- node 5: attention-context GEMVs + epilogues -------------------------
// blocks [0,384)   : out_v tiles (8 t-rows x 64 o-cols)
// blocks [384,576) : out_t tiles (8 n-rows x 64 o-cols)
__global__ __launch_bounds__(256) void k_att(
    const float* __restrict__ At, const float* __restrict__ Av,
    const float* __restrict__ tg, const float* __restrict__ ve,
    const float* __restrict__ vf, const float* __restrict__ tf,
    float* __restrict__ out_v, float* __restrict__ out_t)
{
    __shared__ float attb[768][8];
    __shared__ float pt[4][8][64];
    const int tid = threadIdx.x;
    const int oo = tid & 63, g = tid >> 6;

    if (blockIdx.x < 384) {
        const int bx = blockIdx.x >> 2, by = blockIdx.x & 3;
        const int t0 = bx * 8, o0 = by * 64;
        const int o = o0 + oo;
#pragma unroll
        for (int r = 0; r < 8; ++r) {
            attb[tid][r] = At[(t0 + r)*N + tid];
            if (tid < 128) attb[tid + 256][r] = At[(t0 + r)*N + tid + 256];
        }
        __syncthreads();
        float acc[8] = {0.f,0.f,0.f,0.f,0.f,0.f,0.f,0.f};
#pragma unroll 4
        for (int n = g; n < N; n += 4) {
            float tv = tg[n*D + o];
            float4 a0 = *(const float4*)&attb[n][0];
            float4 a1 = *(const float4*)&attb[n][4];
            acc[0] += a0.x*tv; acc[1] += a0.y*tv; acc[2] += a0.z*tv; acc[3] += a0.w*tv;
            acc[4] += a1.x*tv; acc[5] += a1.y*tv; acc[6] += a1.z*tv; acc[7] += a1.w*tv;
        }
#pragma unroll
        for (int r = 0; r < 8; ++r) pt[g][r][oo] = acc[r];
        __syncthreads();
#pragma unroll
        for (int rr = g; rr < 8; rr += 4) {
            float s = pt[0][rr][oo] + pt[1][rr][oo] + pt[2][rr][oo] + pt[3][rr][oo];
            int t = t0 + rr;
            out_v[t*D + o] = 0.5f*s + 0.5f*ve[t*D + o] + vf[t*D + o];
        }
    } else {
        const int b2 = blockIdx.x - 384;
        const int bx = b2 >> 2, by = b2 & 3;
        const int n0 = bx * 8, o0 = by * 64;
        const int o = o0 + oo;
#pragma unroll
        for (int r = 0; r < 8; ++r) {
            const float* row = Av + (n0 + r)*T;
            attb[tid][r]       = row[tid];
            attb[tid + 256][r] = row[tid + 256];
            attb[tid + 512][r] = row[tid + 512];
        }
        __syncthreads();
        float acc[8] = {0.f,0.f,0.f,0.f,0.f,0.f,0.f,0.f};
#pragma unroll 4
        for (int t = g; t < T; t += 4) {
            float vv = ve[t*D + o];
            float4 a0 = *(const float4*)&attb[t][0];
            float4 a1 = *(const float4*)&attb[t][4];
            acc[0] += a0.x*vv; acc[1] += a0.y*vv; acc[2] += a0.z*vv; acc[3] += a0.w*vv;
            acc[4] += a1.x*vv; acc[5] += a1.y*vv; acc[6] += a1.z*vv; acc[7] += a1.w*vv;
        }
#pragma unroll
        for (int r = 0; r < 8; ++r) pt[g][r][oo] = acc[r];
        __syncthreads();
#pragma unroll
        for (int rr = g; rr < 8; rr += 4) {
            float s = pt[0][rr][oo] + pt[1][rr][oo] + pt[2][rr][oo] + pt[3][rr][oo];
            int n = n0 + rr;
            out_t[n*D + o] = 0.5f*s + 0.5f*tg[n*D + o] + tf[n*D + o];
        }
    }
}

extern "C" void kernel_launch(void* const* d_in, const int* in_sizes, int n_in,
                              void* d_out, int out_size, void* d_ws, size_t ws_size,
                              hipStream_t stream)
{
    (void)in_sizes; (void)n_in; (void)out_size; (void)ws_size;
    const float* vf   = (const float*)d_in[0];
    const float* tf   = (const float*)d_in[1];
    const float* vpos = (const float*)d_in[2];
    const float* tpos = (const float*)d_in[3];
    const float* cw   = (const float*)d_in[4];
    const float* cb   = (const float*)d_in[5];
    const float* bil  = (const float*)d_in[6];
    const float* lw   = (const float*)d_in[7];
    const float* lb   = (const float*)d_in[8];
    const float* W1   = (const float*)d_in[9];
    const float* b1   = (const float*)d_in[10];
    const float* W2   = (const float*)d_in[11];
    const float* Wi   = (const float*)d_in[12];
    // d_in[13]=bi, d_in[15]=bt, d_in[17]=bv: softmax-invariant constant shifts -> unused
    const float* wt   = (const float*)d_in[14];
    const float* wv   = (const float*)d_in[16];

    float* ws  = (float*)d_ws;
    float* ve  = ws;                // T*D
    float* tn  = ve + T*D;          // N*D
    float* tg  = tn + N*D;          // N*D
    float* f1  = tg + N*D;          // T*FD
    float* f2  = f1 + T*FD;         // N*FD
    float* ut  = f2 + N*FD;         // FD
    float* uv  = ut + FD;           // FD
    float* stp = uv + FD;           // 4*T*N
    float* svp = stp + 4*T*N;       // 4*N*T
    float* At  = svp + 4*N*T;       // T*N (normalized)
    float* Av  = At + T*N;          // N*T (normalized)

    float* out_v = (float*)d_out;
    float* out_t = out_v + T*D;

    hipLaunchKernelGGL(k_front, dim3(290),        dim3(256), 0, stream,
                       vf, vpos, cw, cb, W1, b1, tf, tpos, Wi, wt, wv, ve, f1, tn, ut, uv);
    hipLaunchKernelGGL(k_gnnq,  dim3(96),         dim3(256), 0, stream, tn, bil, lw, lb, W2, tg, f2);
    hipLaunchKernelGGL(k_score, dim3(24, 12, 4),  dim3(256), 0, stream, f1, f2, ut, uv, stp, svp);
    hipLaunchKernelGGL(k_stats, dim3(288),        dim3(256), 0, stream, stp, svp, At, Av);
    hipLaunchKernelGGL(k_att,   dim3(576),        dim3(256), 0, stream, At, Av, tg, ve, vf, tf, out_v, out_t);
}

// Round 4
// 139.571 us; speedup vs baseline: 1.5821x; 1.1642x over previous
//
#include <hip/hip_runtime.h>
#include <math.h>

#define D  256
#define T  768
#define N  384
#define FD 512

// ---------- node 1: k_front ----------------------------------------------------
// blocks [0,192)   : conv1d(k=3,pad=1)+ReLU -> ve, then f1 = ve@W1.T+b1 (4-row tiles)
// blocks [192,288) : text row-l2-normalize (4 rows/block, warp per row)
// blocks 288,289   : ut = Wi.T@wt, uv = Wi.T@wv
__global__ __launch_bounds__(256) void k_front(
    const float* __restrict__ vf, const float* __restrict__ vpos,
    const float* __restrict__ cw, const float* __restrict__ cb,
    const float* __restrict__ W1, const float* __restrict__ b1,
    const float* __restrict__ tf, const float* __restrict__ tpos,
    const float* __restrict__ Wi, const float* __restrict__ wt,
    const float* __restrict__ wv,
    float* __restrict__ ve, float* __restrict__ f1,
    float* __restrict__ tn, float* __restrict__ ut, float* __restrict__ uv)
{
    const int b = blockIdx.x, tid = threadIdx.x;
    if (b < 192) {
        __shared__ float vpe[6][D];
        __shared__ float ver[4][D];
        const int t0 = b * 4;
#pragma unroll
        for (int r = 0; r < 6; ++r) {
            int t = t0 - 1 + r;
            float v = 0.f;
            if (t >= 0 && t < T) v = vf[t*D + tid] + vpos[t*D + tid];
            vpe[r][tid] = v;
        }
        __syncthreads();

        float acc[4] = {0.f, 0.f, 0.f, 0.f};
        const float* wrow = cw + tid * (D*3);
        for (int i0 = 0; i0 < D; i0 += 4) {
            float4 w0 = *(const float4*)(wrow + 3*i0);
            float4 w1 = *(const float4*)(wrow + 3*i0 + 4);
            float4 w2 = *(const float4*)(wrow + 3*i0 + 8);
            float w[12] = {w0.x,w0.y,w0.z,w0.w, w1.x,w1.y,w1.z,w1.w, w2.x,w2.y,w2.z,w2.w};
            float4 col[6];
#pragma unroll
            for (int r6 = 0; r6 < 6; ++r6) col[r6] = *(const float4*)&vpe[r6][i0];
            const float* colf = (const float*)col;
#pragma unroll
            for (int di = 0; di < 4; ++di)
#pragma unroll
                for (int k = 0; k < 3; ++k) {
                    float wgt = w[di*3 + k];
#pragma unroll
                    for (int rr = 0; rr < 4; ++rr)
                        acc[rr] += wgt * colf[(rr + k)*4 + di];
                }
        }
        float bias = cb[tid];
#pragma unroll
        for (int rr = 0; rr < 4; ++rr) {
            float v = fmaxf(acc[rr] + bias, 0.f);
            ve[(t0 + rr)*D + tid] = v;
            ver[rr][tid] = v;
        }
        __syncthreads();

        float a0[4] = {0.f,0.f,0.f,0.f}, a1[4] = {0.f,0.f,0.f,0.f};
        const float* w1r0 = W1 + tid * D;
        const float* w1r1 = W1 + (tid + 256) * D;
        for (int d0 = 0; d0 < D; d0 += 4) {
            float4 wa = *(const float4*)(w1r0 + d0);
            float4 wb = *(const float4*)(w1r1 + d0);
#pragma unroll
            for (int rr = 0; rr < 4; ++rr) {
                float4 vv = *(const float4*)&ver[rr][d0];
                a0[rr] += wa.x*vv.x + wa.y*vv.y + wa.z*vv.z + wa.w*vv.w;
                a1[rr] += wb.x*vv.x + wb.y*vv.y + wb.z*vv.z + wb.w*vv.w;
            }
        }
        float bb0 = b1[tid], bb1 = b1[tid + 256];
#pragma unroll
        for (int rr = 0; rr < 4; ++rr) {
            f1[(t0 + rr)*FD + tid]       = a0[rr] + bb0;
            f1[(t0 + rr)*FD + tid + 256] = a1[rr] + bb1;
        }
    } else if (b < 288) {
        const int wid = tid >> 6, lane = tid & 63;
        const int r = (b - 192)*4 + wid;
        float v[4]; float ss = 0.f;
#pragma unroll
        for (int k = 0; k < 4; ++k) {
            v[k] = tf[r*D + lane + 64*k] + tpos[r*D + lane + 64*k];
            ss += v[k]*v[k];
        }
#pragma unroll
        for (int off = 1; off < 64; off <<= 1) ss += __shfl_xor(ss, off);
        float inv = 1.0f / fmaxf(sqrtf(ss), 1e-12f);
#pragma unroll
        for (int k = 0; k < 4; ++k) tn[r*D + lane + 64*k] = v[k] * inv;
    } else {
        __shared__ float wsm[D];
        const float* w = (b == 288) ? wt : wv;
        float* u = (b == 288) ? ut : uv;
        wsm[tid] = w[tid];
        __syncthreads();
        float s0 = 0.f, s1 = 0.f;
#pragma unroll 4
        for (int d = 0; d < D; ++d) {
            float x = wsm[d];
            s0 += x * Wi[d*FD + tid];
            s1 += x * Wi[d*FD + tid + 256];
        }
        u[tid] = s0;
        u[tid + 256] = s1;
    }
}

// ---------- node 2: k_q  (4 blocks x 1024: q = (mean_rows tn) @ bil_w) ----------
__global__ __launch_bounds__(1024) void k_q(
    const float* __restrict__ tn_, const float* __restrict__ bil_w,
    float* __restrict__ q)
{
    __shared__ float part[4][D];
    __shared__ float tb[D];
    __shared__ float qp[16][64];
    const int tid = threadIdx.x;
    const int c = tid & 255, g = tid >> 8;       // g 0..3
    float s = 0.f;
#pragma unroll 8
    for (int n = g; n < N; n += 4) s += tn_[n*D + c];
    part[g][c] = s;
    __syncthreads();
    if (tid < D) tb[tid] = (part[0][tid] + part[1][tid] + part[2][tid] + part[3][tid]) * (1.0f / (float)N);
    __syncthreads();
    const int j = tid & 63, g2 = tid >> 6;       // g2 0..15
    const int cb = blockIdx.x * 64;
    float s2 = 0.f;
#pragma unroll
    for (int e = g2*16; e < g2*16 + 16; ++e) s2 += tb[e] * bil_w[e*D + cb + j];
    qp[g2][j] = s2;
    __syncthreads();
    if (tid < 64) {
        float acc = 0.f;
#pragma unroll
        for (int k = 0; k < 16; ++k) acc += qp[k][tid];
        q[cb + tid] = acc;
    }
}

// ---------- node 3: k_gnn (2 rows/block, 192 blocks) ----------------------------
__global__ __launch_bounds__(256) void k_gnn(
    const float* __restrict__ tn_, const float* __restrict__ q,
    const float* __restrict__ lin_w, const float* __restrict__ lin_b,
    const float* __restrict__ W2,
    float* __restrict__ tg, float* __restrict__ f2)
{
    __shared__ float tns[2][D];
    __shared__ float tgs[2][D];
    __shared__ float qs[D];
    __shared__ float pp[4];
    __shared__ float wgt[2];
    const int tid = threadIdx.x;
    const int n0 = blockIdx.x * 2;
    qs[tid] = q[tid];
    tns[0][tid] = tn_[n0*D + tid];
    tns[1][tid] = tn_[(n0 + 1)*D + tid];
    __syncthreads();

    const int wid = tid >> 6, lane = tid & 63;
    {   // warp wid: row (wid&1), column-half (wid>>1)
        const int r = wid & 1, base = (wid >> 1) * 128;
        float p = tns[r][base + lane] * qs[base + lane]
                + tns[r][base + lane + 64] * qs[base + lane + 64];
#pragma unroll
        for (int off = 32; off; off >>= 1) p += __shfl_down(p, off);
        if (lane == 0) pp[wid] = p;
    }
    __syncthreads();
    if (tid < 2) wgt[tid] = 1.0f / (1.0f + expf(-(pp[tid] + pp[tid + 2])));
    __syncthreads();

    float accl[2] = {0.f, 0.f};
    const float* lwr = lin_w + tid * D;
    for (int d0 = 0; d0 < D; d0 += 4) {
        float4 w4 = *(const float4*)(lwr + d0);
#pragma unroll
        for (int r = 0; r < 2; ++r) {
            float4 tv = *(const float4*)&tns[r][d0];
            accl[r] += w4.x*tv.x + w4.y*tv.y + w4.z*tv.z + w4.w*tv.w;
        }
    }
    float lb = lin_b[tid];
#pragma unroll
    for (int r = 0; r < 2; ++r) {
        float gg = wgt[r] * (accl[r] + lb);
        tgs[r][tid] = gg;
        tg[(n0 + r)*D + tid] = gg;
    }
    __syncthreads();

    float c0[2] = {0.f, 0.f}, c1[2] = {0.f, 0.f};
    const float* w2r0 = W2 + tid * D;
    const float* w2r1 = W2 + (tid + 256) * D;
    for (int d0 = 0; d0 < D; d0 += 4) {
        float4 wa = *(const float4*)(w2r0 + d0);
        float4 wb = *(const float4*)(w2r1 + d0);
#pragma unroll
        for (int r = 0; r < 2; ++r) {
            float4 tv = *(const float4*)&tgs[r][d0];
            c0[r] += wa.x*tv.x + wa.y*tv.y + wa.z*tv.z + wa.w*tv.w;
            c1[r] += wb.x*tv.x + wb.y*tv.y + wb.z*tv.z + wb.w*tv.w;
        }
    }
#pragma unroll
    for (int r = 0; r < 2; ++r) {
        f2[(n0 + r)*FD + tid]       = c0[r];
        f2[(n0 + r)*FD + tid + 256] = c1[r];
    }
}

// ---------- node 4: k_score  (FD split over blockIdx.z, partial outputs) --------
__global__ __launch_bounds__(256) void k_score(
    const float* __restrict__ f1, const float* __restrict__ f2,
    const float* __restrict__ ut, const float* __restrict__ uv,
    float* __restrict__ stp, float* __restrict__ svp)
{
    __shared__ float f1s[32][132];
    __shared__ float f2s[32][132];
    __shared__ float us_t[128];
    __shared__ float us_v[128];
    const int tid = threadIdx.x;
    const int t0 = blockIdx.x * 32, n0 = blockIdx.y * 32, c = blockIdx.z;

    if (tid < 128) { us_t[tid] = ut[c*128 + tid]; us_v[tid] = uv[c*128 + tid]; }
    for (int j = tid; j < 1024; j += 256) {
        int r = j >> 5, c4 = (j & 31) * 4;
        *(float4*)&f1s[r][c4] = *(const float4*)&f1[(t0 + r)*FD + c*128 + c4];
        *(float4*)&f2s[r][c4] = *(const float4*)&f2[(n0 + r)*FD + c*128 + c4];
    }
    __syncthreads();

    const int tA = 2 * (tid >> 4);
    const int nA = tid & 15;

    float at00=0.f, at01=0.f, at10=0.f, at11=0.f;
    float av00=0.f, av01=0.f, av10=0.f, av11=0.f;

#pragma unroll 8
    for (int fq = 0; fq < 32; ++fq) {
        float4 u_t = *(const float4*)&us_t[fq*4];
        float4 u_v = *(const float4*)&us_v[fq*4];
        float4 a0 = *(const float4*)&f1s[tA][fq*4];
        float4 a1 = *(const float4*)&f1s[tA+1][fq*4];
        float4 b0 = *(const float4*)&f2s[nA][fq*4];
        float4 b1 = *(const float4*)&f2s[nA+16][fq*4];
#pragma unroll
        for (int e = 0; e < 4; ++e) {
            float ue_t = ((const float*)&u_t)[e];
            float ue_v = ((const float*)&u_v)[e];
            float a0e = ((const float*)&a0)[e], a1e = ((const float*)&a1)[e];
            float b0e = ((const float*)&b0)[e], b1e = ((const float*)&b1)[e];
            float h00 = fmaxf(a0e + b0e, 0.f);
            float h01 = fmaxf(a0e + b1e, 0.f);
            float h10 = fmaxf(a1e + b0e, 0.f);
            float h11 = fmaxf(a1e + b1e, 0.f);
            at00 += h00*ue_t; av00 += h00*ue_v;
            at01 += h01*ue_t; av01 += h01*ue_v;
            at10 += h10*ue_t; av10 += h10*ue_v;
            at11 += h11*ue_t; av11 += h11*ue_v;
        }
    }
    const int t = t0 + tA, n = n0 + nA;
    float* stz = stp + c * (T*N);
    float* svz = svp + c * (N*T);
    stz[t*N + n]        = at00;  stz[t*N + n + 16]     = at01;
    stz[(t+1)*N + n]    = at10;  stz[(t+1)*N + n + 16] = at11;
    *(float2*)&svz[n*T + t]      = make_float2(av00, av10);
    *(float2*)&svz[(n+16)*T + t] = make_float2(av01, av11);
}

// ---------- node 5: k_att  (combine partials + softmax + context + epilogue) ----
// blocks [0,192)   : out_v tiles (8 t-rows x 128 o-cols; 2 cols/thread)
// blocks [192,288) : out_t tiles (8 n-rows x 128 o-cols; 2 cols/thread)
__global__ __launch_bounds__(256) void k_att(
    const float* __restrict__ stp, const float* __restrict__ svp,
    const float* __restrict__ tg, const float* __restrict__ ve,
    const float* __restrict__ vf, const float* __restrict__ tf,
    float* __restrict__ out_v, float* __restrict__ out_t)
{
    __shared__ float attb[768][8];     // 24 KB
    __shared__ float red[4][8];
    __shared__ float ptA[4][8][64];    // 8 KB
    __shared__ float ptB[4][8][64];    // 8 KB
    const int tid = threadIdx.x;
    const int oo = tid & 63, g = tid >> 6;

    if (blockIdx.x < 192) {
        const int bx = blockIdx.x >> 1, h = blockIdx.x & 1;
        const int t0 = bx * 8;
        const int oA = h*128 + oo, oB = oA + 64;

        float v1[8], v2[8];
#pragma unroll
        for (int r = 0; r < 8; ++r) {
            const float* p = stp + (t0 + r)*N + tid;
            v1[r] = p[0] + p[T*N] + p[2*T*N] + p[3*T*N];
            if (tid < 128) {
                const float* p2 = p + 256;
                v2[r] = p2[0] + p2[T*N] + p2[2*T*N] + p2[3*T*N];
            } else v2[r] = -1e30f;
        }
        float m[8], si[8];
#pragma unroll
        for (int r = 0; r < 8; ++r) {
            float mm = fmaxf(v1[r], v2[r]);
#pragma unroll
            for (int off = 1; off < 64; off <<= 1) mm = fmaxf(mm, __shfl_xor(mm, off));
            if (oo == 0) red[g][r] = mm;
        }
        __syncthreads();
#pragma unroll
        for (int r = 0; r < 8; ++r)
            m[r] = fmaxf(fmaxf(red[0][r], red[1][r]), fmaxf(red[2][r], red[3][r]));
        __syncthreads();
        float e1[8], e2[8];
#pragma unroll
        for (int r = 0; r < 8; ++r) {
            e1[r] = expf(v1[r] - m[r]);
            e2[r] = (tid < 128) ? expf(v2[r] - m[r]) : 0.f;
            float ss = e1[r] + e2[r];
#pragma unroll
            for (int off = 1; off < 64; off <<= 1) ss += __shfl_xor(ss, off);
            if (oo == 0) red[g][r] = ss;
        }
        __syncthreads();
#pragma unroll
        for (int r = 0; r < 8; ++r)
            si[r] = 1.0f / (red[0][r] + red[1][r] + red[2][r] + red[3][r]);
#pragma unroll
        for (int r = 0; r < 8; ++r) {
            attb[tid][r] = e1[r] * si[r];
            if (tid < 128) attb[tid + 256][r] = e2[r] * si[r];
        }
        __syncthreads();

        float accA[8] = {0.f,0.f,0.f,0.f,0.f,0.f,0.f,0.f};
        float accB[8] = {0.f,0.f,0.f,0.f,0.f,0.f,0.f,0.f};
#pragma unroll 4
        for (int n = g; n < N; n += 4) {
            float4 a0 = *(const float4*)&attb[n][0];
            float4 a1 = *(const float4*)&attb[n][4];
            float tvA = tg[n*D + oA], tvB = tg[n*D + oB];
            accA[0] += a0.x*tvA; accA[1] += a0.y*tvA; accA[2] += a0.z*tvA; accA[3] += a0.w*tvA;
            accA[4] += a1.x*tvA; accA[5] += a1.y*tvA; accA[6] += a1.z*tvA; accA[7] += a1.w*tvA;
            accB[0] += a0.x*tvB; accB[1] += a0.y*tvB; accB[2] += a0.z*tvB; accB[3] += a0.w*tvB;
            accB[4] += a1.x*tvB; accB[5] += a1.y*tvB; accB[6] += a1.z*tvB; accB[7] += a1.w*tvB;
        }
#pragma unroll
        for (int r = 0; r < 8; ++r) { ptA[g][r][oo] = accA[r]; ptB[g][r][oo] = accB[r]; }
        __syncthreads();
#pragma unroll
        for (int rr = g; rr < 8; rr += 4) {
            float sA = ptA[0][rr][oo] + ptA[1][rr][oo] + ptA[2][rr][oo] + ptA[3][rr][oo];
            float sB = ptB[0][rr][oo] + ptB[1][rr][oo] + ptB[2][rr][oo] + ptB[3][rr][oo];
            int t = t0 + rr;
            out_v[t*D + oA] = 0.5f*sA + 0.5f*ve[t*D + oA] + vf[t*D + oA];
            out_v[t*D + oB] = 0.5f*sB + 0.5f*ve[t*D + oB] + vf[t*D + oB];
        }
    } else {
        const int b2 = blockIdx.x - 192;
        const int bx = b2 >> 1, h = b2 & 1;
        const int n0 = bx * 8;
        const int oA = h*128 + oo, oB = oA + 64;

        float v1[8], v2[8], v3[8];
#pragma unroll
        for (int r = 0; r < 8; ++r) {
            const float* p = svp + (n0 + r)*T + tid;
            v1[r] = p[0]   + p[N*T]       + p[2*N*T]       + p[3*N*T];
            v2[r] = p[256] + p[N*T + 256] + p[2*N*T + 256] + p[3*N*T + 256];
            v3[r] = p[512] + p[N*T + 512] + p[2*N*T + 512] + p[3*N*T + 512];
        }
        float m[8], si[8];
#pragma unroll
        for (int r = 0; r < 8; ++r) {
            float mm = fmaxf(fmaxf(v1[r], v2[r]), v3[r]);
#pragma unroll
            for (int off = 1; off < 64; off <<= 1) mm = fmaxf(mm, __shfl_xor(mm, off));
            if (oo == 0) red[g][r] = mm;
        }
        __syncthreads();
#pragma unroll
        for (int r = 0; r < 8; ++r)
            m[r] = fmaxf(fmaxf(red[0][r], red[1][r]), fmaxf(red[2][r], red[3][r]));
        __syncthreads();
        float e1[8], e2[8], e3[8];
#pragma unroll
        for (int r = 0; r < 8; ++r) {
            e1[r] = expf(v1[r] - m[r]);
            e2[r] = expf(v2[r] - m[r]);
            e3[r] = expf(v3[r] - m[r]);
            float ss = e1[r] + e2[r] + e3[r];
#pragma unroll
            for (int off = 1; off < 64; off <<= 1) ss += __shfl_xor(ss, off);
            if (oo == 0) red[g][r] = ss;
        }
        __syncthreads();
#pragma unroll
        for (int r = 0; r < 8; ++r)
            si[r] = 1.0f / (red[0][r] + red[1][r] + red[2][r] + red[3][r]);
#pragma unroll
        for (int r = 0; r < 8; ++r) {
            attb[tid][r]       = e1[r] * si[r];
            attb[tid + 256][r] = e2[r] * si[r];
            attb[tid + 512][r] = e3[r] * si[r];
        }
        __syncthreads();

        float accA[8] = {0.f,0.f,0.f,0.f,0.f,0.f,0.f,0.f};
        float accB[8] = {0.f,0.f,0.f,0.f,0.f,0.f,0.f,0.f};
#pragma unroll 4
        for (int t = g; t < T; t += 4) {
            float4 a0 = *(const float4*)&attb[t][0];
            float4 a1 = *(const float4*)&attb[t][4];
            float vvA = ve[t*D + oA], vvB = ve[t*D + oB];
            accA[0] += a0.x*vvA; accA[1] += a0.y*vvA; accA[2] += a0.z*vvA; accA[3] += a0.w*vvA;
            accA[4] += a1.x*vvA; accA[5] += a1.y*vvA; accA[6] += a1.z*vvA; accA[7] += a1.w*vvA;
            accB[0] += a0.x*vvB; accB[1] += a0.y*vvB; accB[2] += a0.z*vvB; accB[3] += a0.w*vvB;
            accB[4] += a1.x*vvB; accB[5] += a1.y*vvB; accB[6] += a1.z*vvB; accB[7] += a1.w*vvB;
        }
#pragma unroll
        for (int r = 0; r < 8; ++r) { ptA[g][r][oo] = accA[r]; ptB[g][r][oo] = accB[r]; }
        __syncthreads();
#pragma unroll
        for (int rr = g; rr < 8; rr += 4) {
            float sA = ptA[0][rr][oo] + ptA[1][rr][oo] + ptA[2][rr][oo] + ptA[3][rr][oo];
            float sB = ptB[0][rr][oo] + ptB[1][rr][oo] + ptB[2][rr][oo] + ptB[3][rr][oo];
            int n = n0 + rr;
            out_t[n*D + oA] = 0.5f*sA + 0.5f*tg[n*D + oA] + tf[n*D + oA];
            out_t[n*D + oB] = 0.5f*sB + 0.5f*tg[n*D + oB] + tf[n*D + oB];
        }
    }
}

extern "C" void kernel_launch(void* const* d_in, const int* in_sizes, int n_in,
                              void* d_out, int out_size, void* d_ws, size_t ws_size,
                              hipStream_t stream)
{
    (void)in_sizes; (void)n_in; (void)out_size; (void)ws_size;
    const float* vf   = (const float*)d_in[0];
    const float* tf   = (const float*)d_in[1];
    const float* vpos = (const float*)d_in[2];
    const float* tpos = (const float*)d_in[3];
    const float* cw   = (const float*)d_in[4];
    const float* cb   = (const float*)d_in[5];
    const float* bil  = (const float*)d_in[6];
    const float* lw   = (const float*)d_in[7];
    const float* lb   = (const float*)d_in[8];
    const float* W1   = (const float*)d_in[9];
    const float* b1   = (const float*)d_in[10];
    const float* W2   = (const float*)d_in[11];
    const float* Wi   = (const float*)d_in[12];
    // d_in[13]=bi, d_in[15]=bt, d_in[17]=bv: softmax-invariant constant shifts -> unused
    const float* wt   = (const float*)d_in[14];
    const float* wv   = (const float*)d_in[16];

    float* ws  = (float*)d_ws;
    float* ve  = ws;                // T*D
    float* tn  = ve + T*D;          // N*D
    float* tg  = tn + N*D;          // N*D
    float* f1  = tg + N*D;          // T*FD
    float* f2  = f1 + T*FD;         // N*FD
    float* q   = f2 + N*FD;         // D
    float* ut  = q + D;             // FD
    float* uv  = ut + FD;           // FD
    float* stp = uv + FD;           // 4*T*N
    float* svp = stp + 4*T*N;       // 4*N*T

    float* out_v = (float*)d_out;
    float* out_t = out_v + T*D;

    hipLaunchKernelGGL(k_front, dim3(290),       dim3(256),  0, stream,
                       vf, vpos, cw, cb, W1, b1, tf, tpos, Wi, wt, wv, ve, f1, tn, ut, uv);
    hipLaunchKernelGGL(k_q,     dim3(4),         dim3(1024), 0, stream, tn, bil, q);
    hipLaunchKernelGGL(k_gnn,   dim3(192),       dim3(256),  0, stream, tn, q, lw, lb, W2, tg, f2);
    hipLaunchKernelGGL(k_score, dim3(24, 12, 4), dim3(256),  0, stream, f1, f2, ut, uv, stp, svp);
    hipLaunchKernelGGL(k_att,   dim3(288),       dim3(256),  0, stream, stp, svp, tg, ve, vf, tf, out_v, out_t);
}